// Round 1
// baseline (771.745 us; speedup 1.0000x reference)
//
#include <hip/hip_runtime.h>
#include <math.h>

typedef unsigned short u16;
typedef unsigned int u32;
typedef __attribute__((ext_vector_type(8))) short bf16x8;
typedef __attribute__((ext_vector_type(4))) float f32x4;

#define S_LEN 2048
#define HID 4096
#define KVD 1024
#define NH 32
#define NKV 8
#define HD 128

__device__ __forceinline__ u16 f2bf(float f) {
  u32 u = __float_as_uint(f);
  u32 r = (u + 0x7FFFu + ((u >> 16) & 1u)) >> 16;
  return (u16)r;
}
__device__ __forceinline__ float bf2f(u16 v) {
  return __uint_as_float(((u32)v) << 16);
}
__device__ __forceinline__ f32x4 mfma16(bf16x8 a, bf16x8 b, f32x4 c) {
  return __builtin_amdgcn_mfma_f32_16x16x32_bf16(a, b, c, 0, 0, 0);
}

// ---------------- fp32 -> bf16 conversion ----------------
__global__ __launch_bounds__(256) void conv_bf16(const float* __restrict__ src,
                                                 u16* __restrict__ dst, int n4) {
  int i = blockIdx.x * 256 + threadIdx.x;
  if (i < n4) {
    float4 v = ((const float4*)src)[i];
    ushort4 o;
    o.x = f2bf(v.x); o.y = f2bf(v.y); o.z = f2bf(v.z); o.w = f2bf(v.w);
    ((ushort4*)dst)[i] = o;
  }
}

// ---------------- GEMM: C[M,N] = A[M,K] * B[N,K]^T (bf16 in, bf16 or fp32 out) ----
#define LDT 40  // padded LDS row (elements); 80B rows -> only free 2-way bank conflicts

__global__ __launch_bounds__(256) void gemm_bt(
    const u16* __restrict__ A, const u16* __restrict__ B,
    u16* __restrict__ Cb, float* __restrict__ Cf,
    int M, int N, int K) {
  __shared__ u16 As[128 * LDT];
  __shared__ u16 Bs[128 * LDT];
  const int tid = threadIdx.x;
  const int lane = tid & 63;
  const int wv = tid >> 6;
  const int cl = lane & 15, qd = lane >> 4;
  const int m0 = blockIdx.y * 128, n0 = blockIdx.x * 128;
  const int wr = (wv >> 1) * 64, wc = (wv & 1) * 64;

  // staging chunks: 512 chunks of 16B per tile, 2 per thread
  const int c0 = tid, c1 = tid + 256;
  const int ar0 = c0 >> 2, ak0 = (c0 & 3) * 8;
  const int ar1 = c1 >> 2, ak1 = (c1 & 3) * 8;

  const u16* Ab = A + (size_t)m0 * K;
  const u16* Bb = B + (size_t)n0 * K;

  f32x4 acc[4][4];
  f32x4 zz = {0.f, 0.f, 0.f, 0.f};
#pragma unroll
  for (int i = 0; i < 4; i++)
#pragma unroll
    for (int j = 0; j < 4; j++) acc[i][j] = zz;

  uint4 ra0 = *(const uint4*)(Ab + (size_t)ar0 * K + ak0);
  uint4 ra1 = *(const uint4*)(Ab + (size_t)ar1 * K + ak1);
  uint4 rb0 = *(const uint4*)(Bb + (size_t)ar0 * K + ak0);
  uint4 rb1 = *(const uint4*)(Bb + (size_t)ar1 * K + ak1);

  for (int kk = 0; kk < K; kk += 32) {
    __syncthreads();
    *(uint4*)&As[ar0 * LDT + ak0] = ra0;
    *(uint4*)&As[ar1 * LDT + ak1] = ra1;
    *(uint4*)&Bs[ar0 * LDT + ak0] = rb0;
    *(uint4*)&Bs[ar1 * LDT + ak1] = rb1;
    __syncthreads();
    if (kk + 32 < K) {  // prefetch next tile into registers, overlap with MFMA
      ra0 = *(const uint4*)(Ab + (size_t)ar0 * K + kk + 32 + ak0);
      ra1 = *(const uint4*)(Ab + (size_t)ar1 * K + kk + 32 + ak1);
      rb0 = *(const uint4*)(Bb + (size_t)ar0 * K + kk + 32 + ak0);
      rb1 = *(const uint4*)(Bb + (size_t)ar1 * K + kk + 32 + ak1);
    }
    bf16x8 af[4], bg[4];
#pragma unroll
    for (int i = 0; i < 4; i++)
      af[i] = *(const bf16x8*)&As[(wr + i * 16 + cl) * LDT + qd * 8];
#pragma unroll
    for (int j = 0; j < 4; j++)
      bg[j] = *(const bf16x8*)&Bs[(wc + j * 16 + cl) * LDT + qd * 8];
#pragma unroll
    for (int i = 0; i < 4; i++)
#pragma unroll
      for (int j = 0; j < 4; j++) acc[i][j] = mfma16(af[i], bg[j], acc[i][j]);
  }

#pragma unroll
  for (int i = 0; i < 4; i++)
#pragma unroll
    for (int j = 0; j < 4; j++) {
      int row = m0 + wr + i * 16 + qd * 4;
      int col = n0 + wc + j * 16 + cl;
#pragma unroll
      for (int r = 0; r < 4; r++) {
        float v = acc[i][j][r];
        if (Cb) Cb[(size_t)(row + r) * N + col] = f2bf(v);
        else    Cf[(size_t)(row + r) * N + col] = v;
      }
    }
}

// ---------------- fused RoPE + L2 norm (in place, bf16) ----------------
// one wave per (s, head); lane d handles pair (d, d+64)
__global__ __launch_bounds__(256) void rope_l2norm(
    u16* __restrict__ x, const int* __restrict__ pos_ids,
    const float* __restrict__ scale, int nheads, int hshift) {
  const int lane = threadIdx.x & 63;
  const int wv = threadIdx.x >> 6;
  const int idx = blockIdx.x * 4 + wv;
  const int s = idx >> hshift;
  const int h = idx & (nheads - 1);
  u16* p = x + (size_t)s * (nheads * HD) + h * HD;
  const float pos = (float)pos_ids[s];
  // inv_freq = 500000^(-d/64) ; -ln(500000)/64 = -0.20503692777194264
  const float inv = expf((float)lane * -0.20503692777194264f);
  const float f = pos * inv;
  float sn, cs;
  sincosf(f, &sn, &cs);
  float a = bf2f(p[lane]);
  float b = bf2f(p[lane + 64]);
  float ra = a * cs - b * sn;
  float rb = b * cs + a * sn;
  float ss = ra * ra + rb * rb;
#pragma unroll
  for (int off = 32; off >= 1; off >>= 1) ss += __shfl_xor(ss, off, 64);
  float rd = 1.0f / (sqrtf(ss) + 1e-6f);
  p[lane] = f2bf(scale[lane] * ra * rd);
  p[lane + 64] = f2bf(scale[lane + 64] * rb * rd);
}

// ---------------- V transpose: [2048][1024] -> [1024][2048] ----------------
__global__ __launch_bounds__(256) void transpose_v(const u16* __restrict__ v,
                                                   u16* __restrict__ vt) {
  __shared__ u16 t[64][65];
  const int r = threadIdx.x >> 6;
  const int c = threadIdx.x & 63;
  const int s0 = blockIdx.x * 64, d0 = blockIdx.y * 64;
#pragma unroll
  for (int i = 0; i < 16; i++) {
    int row = i * 4 + r;
    t[row][c] = v[(size_t)(s0 + row) * KVD + d0 + c];
  }
  __syncthreads();
#pragma unroll
  for (int i = 0; i < 16; i++) {
    int row = i * 4 + r;
    vt[(size_t)(d0 + row) * S_LEN + s0 + c] = t[c][row];
  }
}

// ---------------- causal flash attention (bf16 in/out, fp32 softmax) --------
#define QLD 136  // padded 128-wide rows
#define VLD 72   // padded 64-wide rows
#define PLD 72

__global__ __launch_bounds__(256) void flash_attn(
    const u16* __restrict__ Q, const u16* __restrict__ Kb,
    const u16* __restrict__ Vt, u16* __restrict__ O) {
  __shared__ u16 Qs[64 * QLD];
  __shared__ u16 Ks[64 * QLD];
  __shared__ u16 Vs[128 * VLD];
  __shared__ u16 Ps[64 * PLD];
  const int tid = threadIdx.x;
  const int lane = tid & 63, wv = tid >> 6;
  const int cl = lane & 15, qd = lane >> 4;
  const int qb = blockIdx.x, h = blockIdx.y;
  const int q0 = qb * 64, kvh = h >> 2;

  // stage Q tile [64][128]
#pragma unroll
  for (int it = 0; it < 4; it++) {
    int chunk = tid + it * 256;
    int row = chunk >> 4, off = (chunk & 15) * 8;
    *(uint4*)&Qs[row * QLD + off] =
        *(const uint4*)(Q + (size_t)(q0 + row) * HID + h * HD + off);
  }
  __syncthreads();
  bf16x8 aQ[4];  // this wave's 16 q-rows, all of K=128, kept in registers
#pragma unroll
  for (int kk = 0; kk < 4; kk++)
    aQ[kk] = *(const bf16x8*)&Qs[(wv * 16 + cl) * QLD + kk * 32 + qd * 8];

  f32x4 oacc[8];
  f32x4 zz = {0.f, 0.f, 0.f, 0.f};
#pragma unroll
  for (int n = 0; n < 8; n++) oacc[n] = zz;
  float mrow[4], lrow[4];
#pragma unroll
  for (int r = 0; r < 4; r++) { mrow[r] = -__builtin_inff(); lrow[r] = 0.f; }
  const float sc = 0.08838834764831845f;  // 1/sqrt(128)

  for (int kt = 0; kt <= qb; kt++) {
    __syncthreads();  // previous iteration's PV reads of Ks/Vs done
#pragma unroll
    for (int it = 0; it < 4; it++) {
      int chunk = tid + it * 256;
      int row = chunk >> 4, off = (chunk & 15) * 8;
      *(uint4*)&Ks[row * QLD + off] =
          *(const uint4*)(Kb + (size_t)(kt * 64 + row) * KVD + kvh * HD + off);
    }
#pragma unroll
    for (int it = 0; it < 4; it++) {
      int chunk = tid + it * 256;
      int row = chunk >> 3, off = (chunk & 7) * 8;
      *(uint4*)&Vs[row * VLD + off] =
          *(const uint4*)(Vt + (size_t)(kvh * HD + row) * S_LEN + kt * 64 + off);
    }
    __syncthreads();

    // S = Q K^T : this wave's 16 q-rows x 64 key cols
    f32x4 sacc[4];
#pragma unroll
    for (int j = 0; j < 4; j++) sacc[j] = zz;
#pragma unroll
    for (int j = 0; j < 4; j++)
#pragma unroll
      for (int kk = 0; kk < 4; kk++) {
        bf16x8 bK = *(const bf16x8*)&Ks[(j * 16 + cl) * QLD + kk * 32 + qd * 8];
        sacc[j] = mfma16(aQ[kk], bK, sacc[j]);
      }

    const int grow = q0 + wv * 16 + qd * 4;
    float pm[4][4];
    float mnew[4];
#pragma unroll
    for (int r = 0; r < 4; r++) mnew[r] = mrow[r];
#pragma unroll
    for (int j = 0; j < 4; j++) {
      int gcol = kt * 64 + j * 16 + cl;
#pragma unroll
      for (int r = 0; r < 4; r++) {
        float sv = (gcol <= grow + r) ? sacc[j][r] * sc : -3.0e38f;
        pm[j][r] = sv;
        mnew[r] = fmaxf(mnew[r], sv);
      }
    }
#pragma unroll
    for (int r = 0; r < 4; r++) {
#pragma unroll
      for (int off = 8; off >= 1; off >>= 1)
        mnew[r] = fmaxf(mnew[r], __shfl_xor(mnew[r], off, 64));
    }
    float alpha[4], rsum[4];
#pragma unroll
    for (int r = 0; r < 4; r++) {
      alpha[r] = expf(mrow[r] - mnew[r]);
      mrow[r] = mnew[r];
      rsum[r] = 0.f;
    }
#pragma unroll
    for (int j = 0; j < 4; j++)
#pragma unroll
      for (int r = 0; r < 4; r++) {
        float pp = expf(pm[j][r] - mnew[r]);
        pm[j][r] = pp;
        rsum[r] += pp;
      }
#pragma unroll
    for (int r = 0; r < 4; r++) {
#pragma unroll
      for (int off = 8; off >= 1; off >>= 1)
        rsum[r] += __shfl_xor(rsum[r], off, 64);
      lrow[r] = lrow[r] * alpha[r] + rsum[r];
    }
#pragma unroll
    for (int n = 0; n < 8; n++)
#pragma unroll
      for (int r = 0; r < 4; r++) oacc[n][r] *= alpha[r];
    // P: C-layout -> LDS -> A-layout (each wave owns its 16-row strip)
#pragma unroll
    for (int j = 0; j < 4; j++)
#pragma unroll
      for (int r = 0; r < 4; r++)
        Ps[(wv * 16 + qd * 4 + r) * PLD + j * 16 + cl] = f2bf(pm[j][r]);
    __syncthreads();  // LDS ordering fence (cheap; protects P write->read)
#pragma unroll
    for (int kk = 0; kk < 2; kk++) {
      bf16x8 aP = *(const bf16x8*)&Ps[(wv * 16 + cl) * PLD + kk * 32 + qd * 8];
#pragma unroll
      for (int n = 0; n < 8; n++) {
        bf16x8 bV = *(const bf16x8*)&Vs[(n * 16 + cl) * VLD + kk * 32 + qd * 8];
        oacc[n] = mfma16(aP, bV, oacc[n]);
      }
    }
  }
#pragma unroll
  for (int r = 0; r < 4; r++) {
    float il = 1.0f / lrow[r];
#pragma unroll
    for (int n = 0; n < 8; n++) {
      int row = q0 + wv * 16 + qd * 4 + r;
      int col = h * HD + n * 16 + cl;
      O[(size_t)row * HID + col] = f2bf(oacc[n][r] * il);
    }
  }
}

// ---------------- launch ----------------
extern "C" void kernel_launch(void* const* d_in, const int* in_sizes, int n_in,
                              void* d_out, int out_size, void* d_ws, size_t ws_size,
                              hipStream_t stream) {
  const float* hs = (const float*)d_in[0];
  const int* pos = (const int*)d_in[1];
  const float* Wq = (const float*)d_in[2];
  const float* Wk = (const float*)d_in[3];
  const float* Wv = (const float*)d_in[4];
  const float* Wo = (const float*)d_in[5];
  const float* qsc = (const float*)d_in[6];
  const float* ksc = (const float*)d_in[7];
  float* out = (float*)d_out;
  char* ws = (char*)d_ws;
  const size_t MB = 1u << 20;

  u16* hs_b = (u16*)(ws + 0 * MB);   // 16 MB; later reused for attention output
  u16* w_b  = (u16*)(ws + 16 * MB);  // 32 MB; Wq then Wo
  u16* wk_b = (u16*)(ws + 48 * MB);  // 8 MB
  u16* wv_b = (u16*)(ws + 56 * MB);  // 8 MB
  u16* q_b  = (u16*)(ws + 64 * MB);  // 16 MB
  u16* k_b  = (u16*)(ws + 80 * MB);  // 4 MB
  u16* v_b  = (u16*)(ws + 84 * MB);  // 4 MB
  u16* vt_b = (u16*)(ws + 88 * MB);  // 4 MB
  u16* o_b  = hs_b;                  // safe: hs consumed before attention

  const int n_hs = S_LEN * HID;       // 8388608
  const int n_wq = HID * HID;         // 16777216
  const int n_wk = KVD * HID;         // 4194304

  conv_bf16<<<(n_hs / 4 + 255) / 256, 256, 0, stream>>>(hs, hs_b, n_hs / 4);
  conv_bf16<<<(n_wq / 4 + 255) / 256, 256, 0, stream>>>(Wq, w_b, n_wq / 4);
  conv_bf16<<<(n_wk / 4 + 255) / 256, 256, 0, stream>>>(Wk, wk_b, n_wk / 4);
  conv_bf16<<<(n_wk / 4 + 255) / 256, 256, 0, stream>>>(Wv, wv_b, n_wk / 4);

  gemm_bt<<<dim3(HID / 128, S_LEN / 128), 256, 0, stream>>>(
      hs_b, w_b, q_b, nullptr, S_LEN, HID, HID);
  gemm_bt<<<dim3(KVD / 128, S_LEN / 128), 256, 0, stream>>>(
      hs_b, wk_b, k_b, nullptr, S_LEN, KVD, HID);
  gemm_bt<<<dim3(KVD / 128, S_LEN / 128), 256, 0, stream>>>(
      hs_b, wv_b, v_b, nullptr, S_LEN, KVD, HID);

  rope_l2norm<<<S_LEN * NH / 4, 256, 0, stream>>>(q_b, pos, qsc, NH, 5);
  rope_l2norm<<<S_LEN * NKV / 4, 256, 0, stream>>>(k_b, pos, ksc, NKV, 3);
  transpose_v<<<dim3(S_LEN / 64, KVD / 64), 256, 0, stream>>>(v_b, vt_b);

  conv_bf16<<<(n_wq / 4 + 255) / 256, 256, 0, stream>>>(Wo, w_b, n_wq / 4);

  flash_attn<<<dim3(S_LEN / 64, NH), 256, 0, stream>>>(q_b, k_b, vt_b, o_b);

  gemm_bt<<<dim3(HID / 128, S_LEN / 128), 256, 0, stream>>>(
      o_b, w_b, nullptr, out, S_LEN, HID, HID);
}

// Round 2
// 591.196 us; speedup vs baseline: 1.3054x; 1.3054x over previous
//
#include <hip/hip_runtime.h>
#include <math.h>

typedef unsigned short u16;
typedef unsigned int u32;
typedef __attribute__((ext_vector_type(8))) short bf16x8;
typedef __attribute__((ext_vector_type(4))) float f32x4;

#define S_LEN 2048
#define HID 4096
#define NH 32
#define NKV 8
#define HD 128
#define QS 6144  // fused qkv row stride (4096 Q | 1024 K | 1024 V)

__device__ __forceinline__ u16 f2bf(float f) {
  u32 u = __float_as_uint(f);
  u32 r = (u + 0x7FFFu + ((u >> 16) & 1u)) >> 16;
  return (u16)r;
}
__device__ __forceinline__ float bf2f(u16 v) {
  return __uint_as_float(((u32)v) << 16);
}
__device__ __forceinline__ f32x4 mfma16(bf16x8 a, bf16x8 b, f32x4 c) {
  return __builtin_amdgcn_mfma_f32_16x16x32_bf16(a, b, c, 0, 0, 0);
}
// async global->LDS, 16B per lane. LDS dest is wave-uniform base + lane*16.
__device__ __forceinline__ void async16(const u16* g, u16* l) {
  __builtin_amdgcn_global_load_lds(
      (__attribute__((address_space(1))) void*)g,
      (__attribute__((address_space(3))) void*)l, 16, 0, 0);
}
#if __has_builtin(__builtin_amdgcn_exp2f)
#define EXP2(x) __builtin_amdgcn_exp2f(x)
#else
#define EXP2(x) exp2f(x)
#endif

// ---------------- fp32 -> bf16 conversion ----------------
__global__ __launch_bounds__(256) void conv_bf16(const float* __restrict__ src,
                                                 u16* __restrict__ dst, int n4) {
  int i = blockIdx.x * 256 + threadIdx.x;
  if (i < n4) {
    float4 v = ((const float4*)src)[i];
    ushort4 o;
    o.x = f2bf(v.x); o.y = f2bf(v.y); o.z = f2bf(v.z); o.w = f2bf(v.w);
    ((ushort4*)dst)[i] = o;
  }
}

// ---------------- GEMM: C[M,N] = A[M,K] * B[N,K]^T, m97 recipe ----------------
// LDS tiles [128 rows][32 k] unpadded; staged with global_load_lds width=16.
// Fragment-read bank classes are even (8 touches/bank) for this layout.
__global__ __launch_bounds__(256) void gemm_bt(
    const u16* __restrict__ A, const u16* __restrict__ B,
    u16* __restrict__ Cb, float* __restrict__ Cf,
    int M, int N, int K) {
  __shared__ u16 As[4096];
  __shared__ u16 Bs[4096];
  const int tid = threadIdx.x;
  const int lane = tid & 63, wv = tid >> 6;
  const int cl = lane & 15, qd = lane >> 4;
  const int m0 = blockIdx.y * 128, n0 = blockIdx.x * 128;
  const int wr = (wv >> 1) * 64, wc = (wv & 1) * 64;
  // staging chunk c = tid: row=c>>2, koff=(c&3)*8; second chunk = +64 rows
  const int r0 = tid >> 2, k0 = (tid & 3) * 8;
  const u16* Ap = A + (size_t)(m0 + r0) * K + k0;
  const u16* Bp = B + (size_t)(n0 + r0) * K + k0;
  u16* As0 = As + wv * 512;  // wave-uniform LDS bases
  u16* Bs0 = Bs + wv * 512;

  f32x4 acc[4][4];
  f32x4 zz = {0.f, 0.f, 0.f, 0.f};
#pragma unroll
  for (int i = 0; i < 4; i++)
#pragma unroll
    for (int j = 0; j < 4; j++) acc[i][j] = zz;

  for (int kk = 0; kk < K; kk += 32) {
    __syncthreads();  // prior tile's reads complete
    async16(Ap + kk, As0);
    async16(Ap + (size_t)64 * K + kk, As0 + 2048);
    async16(Bp + kk, Bs0);
    async16(Bp + (size_t)64 * K + kk, Bs0 + 2048);
    __syncthreads();  // vmcnt(0) drain: tile ready
    bf16x8 af[4], bg[4];
#pragma unroll
    for (int i = 0; i < 4; i++)
      af[i] = *(const bf16x8*)&As[(wr + i * 16 + cl) * 32 + qd * 8];
#pragma unroll
    for (int j = 0; j < 4; j++)
      bg[j] = *(const bf16x8*)&Bs[(wc + j * 16 + cl) * 32 + qd * 8];
#pragma unroll
    for (int i = 0; i < 4; i++)
#pragma unroll
      for (int j = 0; j < 4; j++) acc[i][j] = mfma16(af[i], bg[j], acc[i][j]);
  }

#pragma unroll
  for (int i = 0; i < 4; i++)
#pragma unroll
    for (int j = 0; j < 4; j++) {
      int row = m0 + wr + i * 16 + qd * 4;
      int col = n0 + wc + j * 16 + cl;
#pragma unroll
      for (int r = 0; r < 4; r++) {
        float v = acc[i][j][r];
        if (Cb) Cb[(size_t)(row + r) * N + col] = f2bf(v);
        else    Cf[(size_t)(row + r) * N + col] = v;
      }
    }
}

// ---------------- fused RoPE + L2 norm (in place, bf16, strided) -------------
__global__ __launch_bounds__(256) void rope_l2norm(
    u16* __restrict__ x, const int* __restrict__ pos_ids,
    const float* __restrict__ scale, int hmask, int hshift, int stride) {
  const int lane = threadIdx.x & 63;
  const int wv = threadIdx.x >> 6;
  const int idx = blockIdx.x * 4 + wv;
  const int s = idx >> hshift;
  const int h = idx & hmask;
  u16* p = x + (size_t)s * stride + h * HD;
  const float pos = (float)pos_ids[s];
  const float inv = expf((float)lane * -0.20503692777194264f);  // 5e5^(-d/64)
  float sn, cs;
  sincosf(pos * inv, &sn, &cs);
  float a = bf2f(p[lane]);
  float b = bf2f(p[lane + 64]);
  float ra = a * cs - b * sn;
  float rb = b * cs + a * sn;
  float ss = ra * ra + rb * rb;
#pragma unroll
  for (int off = 32; off >= 1; off >>= 1) ss += __shfl_xor(ss, off, 64);
  float rd = 1.0f / (sqrtf(ss) + 1e-6f);
  p[lane] = f2bf(scale[lane] * ra * rd);
  p[lane + 64] = f2bf(scale[lane + 64] * rb * rd);
}

// ---------------- V transpose: qkv V-cols [2048][1024@stride] -> [1024][2048]
__global__ __launch_bounds__(256) void transpose_v(const u16* __restrict__ v,
                                                   u16* __restrict__ vt) {
  __shared__ u16 t[64][65];
  const int r = threadIdx.x >> 6;
  const int c = threadIdx.x & 63;
  const int s0 = blockIdx.x * 64, d0 = blockIdx.y * 64;
#pragma unroll
  for (int i = 0; i < 16; i++) {
    int row = i * 4 + r;
    t[row][c] = v[(size_t)(s0 + row) * QS + d0 + c];
  }
  __syncthreads();
#pragma unroll
  for (int i = 0; i < 16; i++) {
    int row = i * 4 + r;
    vt[(size_t)(d0 + row) * S_LEN + s0 + c] = t[c][row];
  }
}

// ---------------- causal flash attention -------------------------------------
// No online max: q,k are L2-normalized (scale=1) so |score*sc| <= 0.0884 —
// exp2 cannot overflow; masked tiles only on the diagonal. Row sums kept as
// lane-local partials, reduced once at the end.
#define PLD 68  // padded P rows (136B) -> even bank distribution

__global__ __launch_bounds__(256) void flash_attn(
    const u16* __restrict__ QKV, const u16* __restrict__ Vt,
    u16* __restrict__ O) {
  __shared__ u16 Ks[64 * 128];   // XOR-swizzled chunks: slot = row*16 + (c ^ (row&15))
  __shared__ u16 Vs[128 * 64];   // [d][s] swizzled: slot = row*8 + (c ^ (row&7))
  __shared__ u16 Ps[64 * PLD];
  const int tid = threadIdx.x;
  const int lane = tid & 63, wv = tid >> 6;
  const int cl = lane & 15, qd = lane >> 4;
  const int qb = blockIdx.x, h = blockIdx.y;
  const int q0 = qb * 64, kvh = h >> 2;
  const float es = 0.12751629240081506f;  // (1/sqrt(128)) * log2(e)

  // Q fragments straight from global (no LDS staging)
  bf16x8 aQ[4];
  {
    const u16* qrow = QKV + (size_t)(q0 + wv * 16 + cl) * QS + h * HD + qd * 8;
#pragma unroll
    for (int kk = 0; kk < 4; kk++) aQ[kk] = *(const bf16x8*)(qrow + kk * 32);
  }

  f32x4 oacc[8];
  f32x4 zz = {0.f, 0.f, 0.f, 0.f};
#pragma unroll
  for (int n = 0; n < 8; n++) oacc[n] = zz;
  float lsum[4] = {0.f, 0.f, 0.f, 0.f};

  const u16* Kbase = QKV + 4096 + kvh * HD;            // key rows, stride QS
  const u16* Vbase = Vt + (size_t)kvh * HD * S_LEN;    // [d][s], stride S_LEN

  for (int kt = 0; kt <= qb; kt++) {
    __syncthreads();  // prior iteration's Ks/Vs reads done
#pragma unroll
    for (int q = 0; q < 4; q++) {
      int c = q * 256 + wv * 64 + lane;
      int kr = c >> 4, kg = (c & 15) ^ (kr & 15);
      async16(Kbase + (size_t)(kt * 64 + kr) * QS + kg * 8,
              Ks + q * 2048 + wv * 512);
      int vr = c >> 3, vg = (c & 7) ^ (vr & 7);
      async16(Vbase + (size_t)vr * S_LEN + kt * 64 + vg * 8,
              Vs + q * 2048 + wv * 512);
    }
    __syncthreads();  // vmcnt(0) drain

    // S = Q K^T (this wave: 16 q-rows x 64 keys)
    f32x4 sacc[4];
#pragma unroll
    for (int j = 0; j < 4; j++) sacc[j] = zz;
#pragma unroll
    for (int j = 0; j < 4; j++) {
      int row = j * 16 + cl;
#pragma unroll
      for (int kk = 0; kk < 4; kk++) {
        int ch = (kk * 4 + qd) ^ (row & 15);
        bf16x8 bK = *(const bf16x8*)&Ks[row * 128 + ch * 8];
        sacc[j] = mfma16(aQ[kk], bK, sacc[j]);
      }
    }

    // softmax numerators (no max subtraction needed; see header comment)
    float pm[4][4];
    if (kt == qb) {  // diagonal tile: causal mask
      const int grow = q0 + wv * 16 + qd * 4;
#pragma unroll
      for (int j = 0; j < 4; j++) {
        int gcol = kt * 64 + j * 16 + cl;
#pragma unroll
        for (int r = 0; r < 4; r++)
          pm[j][r] = (gcol <= grow + r) ? EXP2(sacc[j][r] * es) : 0.f;
      }
    } else {
#pragma unroll
      for (int j = 0; j < 4; j++)
#pragma unroll
        for (int r = 0; r < 4; r++) pm[j][r] = EXP2(sacc[j][r] * es);
    }
#pragma unroll
    for (int j = 0; j < 4; j++)
#pragma unroll
      for (int r = 0; r < 4; r++) lsum[r] += pm[j][r];

    // P: C-layout -> LDS (A-layout for PV)
#pragma unroll
    for (int j = 0; j < 4; j++)
#pragma unroll
      for (int r = 0; r < 4; r++)
        Ps[(wv * 16 + qd * 4 + r) * PLD + j * 16 + cl] = f2bf(pm[j][r]);
    __syncthreads();

    // O += P V
#pragma unroll
    for (int kk = 0; kk < 2; kk++) {
      bf16x8 aP = *(const bf16x8*)&Ps[(wv * 16 + cl) * PLD + kk * 32 + qd * 8];
#pragma unroll
      for (int n = 0; n < 8; n++) {
        int row = n * 16 + cl;
        int ch = (kk * 4 + qd) ^ (row & 7);
        bf16x8 bV = *(const bf16x8*)&Vs[row * 64 + ch * 8];
        oacc[n] = mfma16(aP, bV, oacc[n]);
      }
    }
  }

  // reduce row sums across the 16-lane column group, write O
#pragma unroll
  for (int r = 0; r < 4; r++) {
#pragma unroll
    for (int off = 8; off >= 1; off >>= 1) lsum[r] += __shfl_xor(lsum[r], off, 64);
  }
#pragma unroll
  for (int r = 0; r < 4; r++) {
    float il = 1.0f / lsum[r];
    int row = q0 + wv * 16 + qd * 4 + r;
#pragma unroll
    for (int n = 0; n < 8; n++)
      O[(size_t)row * HID + h * HD + n * 16 + cl] = f2bf(oacc[n][r] * il);
  }
}

// ---------------- launch ----------------
extern "C" void kernel_launch(void* const* d_in, const int* in_sizes, int n_in,
                              void* d_out, int out_size, void* d_ws, size_t ws_size,
                              hipStream_t stream) {
  const float* hs = (const float*)d_in[0];
  const int* pos = (const int*)d_in[1];
  const float* Wq = (const float*)d_in[2];
  const float* Wk = (const float*)d_in[3];
  const float* Wv = (const float*)d_in[4];
  const float* Wo = (const float*)d_in[5];
  const float* qsc = (const float*)d_in[6];
  const float* ksc = (const float*)d_in[7];
  float* out = (float*)d_out;
  char* ws = (char*)d_ws;
  const size_t MB = 1u << 20;

  u16* hs_b  = (u16*)(ws + 0 * MB);   // 16 MB; reused for attention output
  u16* wq_b  = (u16*)(ws + 16 * MB);  // 32 MB (Wq) — reused for Wo after qkv gemm
  u16* wk_b  = (u16*)(ws + 48 * MB);  // 8 MB  } contiguous with wq -> B[6144][4096]
  u16* wv_b  = (u16*)(ws + 56 * MB);  // 8 MB  }
  u16* qkv_b = (u16*)(ws + 64 * MB);  // 24 MB: [2048][6144] = Q|K|V
  u16* vt_b  = (u16*)(ws + 88 * MB);  // 4 MB: V^T [1024][2048]
  u16* o_b   = hs_b;                  // hs dead after qkv gemm
  u16* wo_b  = wq_b;                  // wq dead after qkv gemm

  const int n_hs = S_LEN * HID;   // 8.39M
  const int n_wq = HID * HID;     // 16.8M
  const int n_wk = (NKV * HD) * HID;  // 4.19M

  conv_bf16<<<(n_hs / 4 + 255) / 256, 256, 0, stream>>>(hs, hs_b, n_hs / 4);
  conv_bf16<<<(n_wq / 4 + 255) / 256, 256, 0, stream>>>(Wq, wq_b, n_wq / 4);
  conv_bf16<<<(n_wk / 4 + 255) / 256, 256, 0, stream>>>(Wk, wk_b, n_wk / 4);
  conv_bf16<<<(n_wk / 4 + 255) / 256, 256, 0, stream>>>(Wv, wv_b, n_wk / 4);

  // fused QKV projection: [2048][4096] x [6144][4096]^T -> [2048][6144]
  gemm_bt<<<dim3(QS / 128, S_LEN / 128), 256, 0, stream>>>(
      hs_b, wq_b, qkv_b, nullptr, S_LEN, QS, HID);

  conv_bf16<<<(n_wq / 4 + 255) / 256, 256, 0, stream>>>(Wo, wo_b, n_wq / 4);

  rope_l2norm<<<S_LEN * NH / 4, 256, 0, stream>>>(qkv_b, pos, qsc, NH - 1, 5, QS);
  rope_l2norm<<<S_LEN * NKV / 4, 256, 0, stream>>>(qkv_b + 4096, pos, ksc, NKV - 1, 3, QS);
  transpose_v<<<dim3(S_LEN / 64, (NKV * HD) / 64), 256, 0, stream>>>(qkv_b + 5120, vt_b);

  flash_attn<<<dim3(S_LEN / 64, NH), 256, 0, stream>>>(qkv_b, vt_b, o_b);

  gemm_bt<<<dim3(HID / 128, S_LEN / 128), 256, 0, stream>>>(
      o_b, wo_b, nullptr, out, S_LEN, HID, HID);
}

// Round 3
// 547.169 us; speedup vs baseline: 1.4104x; 1.0805x over previous
//
#include <hip/hip_runtime.h>
#include <math.h>

typedef unsigned short u16;
typedef unsigned int u32;
typedef __attribute__((ext_vector_type(8))) short bf16x8;
typedef __attribute__((ext_vector_type(4))) float f32x4;

#define S_LEN 2048
#define HID 4096
#define NH 32
#define NKV 8
#define HD 128
#define QS 6144  // fused qkv row stride (4096 Q | 1024 K | 1024 V)

__device__ __forceinline__ u16 f2bf(float f) {
  u32 u = __float_as_uint(f);
  u32 r = (u + 0x7FFFu + ((u >> 16) & 1u)) >> 16;
  return (u16)r;
}
__device__ __forceinline__ float bf2f(u16 v) {
  return __uint_as_float(((u32)v) << 16);
}
__device__ __forceinline__ f32x4 mfma16(bf16x8 a, bf16x8 b, f32x4 c) {
  return __builtin_amdgcn_mfma_f32_16x16x32_bf16(a, b, c, 0, 0, 0);
}
// async global->LDS, 16B per lane. LDS dest is wave-uniform base + lane*16.
__device__ __forceinline__ void async16(const u16* g, u16* l) {
  __builtin_amdgcn_global_load_lds(
      (__attribute__((address_space(1))) void*)g,
      (__attribute__((address_space(3))) void*)l, 16, 0, 0);
}
#if __has_builtin(__builtin_amdgcn_exp2f)
#define EXP2(x) __builtin_amdgcn_exp2f(x)
#else
#define EXP2(x) exp2f(x)
#endif

// ---------------- fp32 -> bf16, all five tensors in one launch ---------------
// region sizes (float4 units): hs 2097152 | wq 4194304 | wk 1048576 |
// wv 1048576 | wo 4194304 ; all multiples of 256 so branches are block-uniform
__global__ __launch_bounds__(256) void conv_all(
    const float* __restrict__ hs, const float* __restrict__ wq,
    const float* __restrict__ wk, const float* __restrict__ wv,
    const float* __restrict__ wo, u16* __restrict__ dhs, u16* __restrict__ dwq,
    u16* __restrict__ dwk, u16* __restrict__ dwv, u16* __restrict__ dwo) {
  int i = blockIdx.x * 256 + threadIdx.x;
  const float* src;
  u16* dst;
  int off;
  if (i < 2097152) { src = hs; dst = dhs; off = 0; }
  else if (i < 6291456) { src = wq; dst = dwq; off = 2097152; }
  else if (i < 7340032) { src = wk; dst = dwk; off = 6291456; }
  else if (i < 8388608) { src = wv; dst = dwv; off = 7340032; }
  else { src = wo; dst = dwo; off = 8388608; }
  int j = i - off;
  float4 v = ((const float4*)src)[j];
  ushort4 o;
  o.x = f2bf(v.x); o.y = f2bf(v.y); o.z = f2bf(v.z); o.w = f2bf(v.w);
  ((ushort4*)dst)[j] = o;
}

// ---------------- GEMM: C[M,N] = A[M,K] * B[N,K]^T, m97 recipe ----------------
__global__ __launch_bounds__(256) void gemm_bt(
    const u16* __restrict__ A, const u16* __restrict__ B,
    u16* __restrict__ Cb, float* __restrict__ Cf,
    int M, int N, int K) {
  __shared__ u16 As[4096];
  __shared__ u16 Bs[4096];
  const int tid = threadIdx.x;
  const int lane = tid & 63, wv = tid >> 6;
  const int cl = lane & 15, qd = lane >> 4;
  const int m0 = blockIdx.y * 128, n0 = blockIdx.x * 128;
  const int wr = (wv >> 1) * 64, wc = (wv & 1) * 64;
  const int r0 = tid >> 2, k0 = (tid & 3) * 8;
  const u16* Ap = A + (size_t)(m0 + r0) * K + k0;
  const u16* Bp = B + (size_t)(n0 + r0) * K + k0;
  u16* As0 = As + wv * 512;  // wave-uniform LDS bases
  u16* Bs0 = Bs + wv * 512;

  f32x4 acc[4][4];
  f32x4 zz = {0.f, 0.f, 0.f, 0.f};
#pragma unroll
  for (int i = 0; i < 4; i++)
#pragma unroll
    for (int j = 0; j < 4; j++) acc[i][j] = zz;

  for (int kk = 0; kk < K; kk += 32) {
    __syncthreads();
    async16(Ap + kk, As0);
    async16(Ap + (size_t)64 * K + kk, As0 + 2048);
    async16(Bp + kk, Bs0);
    async16(Bp + (size_t)64 * K + kk, Bs0 + 2048);
    __syncthreads();
    bf16x8 af[4], bg[4];
#pragma unroll
    for (int i = 0; i < 4; i++)
      af[i] = *(const bf16x8*)&As[(wr + i * 16 + cl) * 32 + qd * 8];
#pragma unroll
    for (int j = 0; j < 4; j++)
      bg[j] = *(const bf16x8*)&Bs[(wc + j * 16 + cl) * 32 + qd * 8];
#pragma unroll
    for (int i = 0; i < 4; i++)
#pragma unroll
      for (int j = 0; j < 4; j++) acc[i][j] = mfma16(af[i], bg[j], acc[i][j]);
  }

#pragma unroll
  for (int i = 0; i < 4; i++)
#pragma unroll
    for (int j = 0; j < 4; j++) {
      int row = m0 + wr + i * 16 + qd * 4;
      int col = n0 + wc + j * 16 + cl;
#pragma unroll
      for (int r = 0; r < 4; r++) {
        float v = acc[i][j][r];
        if (Cb) Cb[(size_t)(row + r) * N + col] = f2bf(v);
        else    Cf[(size_t)(row + r) * N + col] = v;
      }
    }
}

// ---------------- fused RoPE + L2 norm (in place, bf16, strided) -------------
__global__ __launch_bounds__(256) void rope_l2norm(
    u16* __restrict__ x, const int* __restrict__ pos_ids,
    const float* __restrict__ scale, int hmask, int hshift, int stride) {
  const int lane = threadIdx.x & 63;
  const int wv = threadIdx.x >> 6;
  const int idx = blockIdx.x * 4 + wv;
  const int s = idx >> hshift;
  const int h = idx & hmask;
  u16* p = x + (size_t)s * stride + h * HD;
  const float pos = (float)pos_ids[s];
  const float inv = expf((float)lane * -0.20503692777194264f);  // 5e5^(-d/64)
  float sn, cs;
  sincosf(pos * inv, &sn, &cs);
  float a = bf2f(p[lane]);
  float b = bf2f(p[lane + 64]);
  float ra = a * cs - b * sn;
  float rb = b * cs + a * sn;
  float ss = ra * ra + rb * rb;
#pragma unroll
  for (int off = 32; off >= 1; off >>= 1) ss += __shfl_xor(ss, off, 64);
  float rd = 1.0f / (sqrtf(ss) + 1e-6f);
  p[lane] = f2bf(scale[lane] * ra * rd);
  p[lane + 64] = f2bf(scale[lane + 64] * rb * rd);
}

// ---------------- V transpose: qkv V-cols [2048][1024@QS] -> [1024][2048] ----
__global__ __launch_bounds__(256) void transpose_v(const u16* __restrict__ v,
                                                   u16* __restrict__ vt) {
  __shared__ u16 t[64][65];
  const int r = threadIdx.x >> 6;
  const int c = threadIdx.x & 63;
  const int s0 = blockIdx.x * 64, d0 = blockIdx.y * 64;
#pragma unroll
  for (int i = 0; i < 16; i++) {
    int row = i * 4 + r;
    t[row][c] = v[(size_t)(s0 + row) * QS + d0 + c];
  }
  __syncthreads();
#pragma unroll
  for (int i = 0; i < 16; i++) {
    int row = i * 4 + r;
    vt[(size_t)(d0 + row) * S_LEN + s0 + c] = t[c][row];
  }
}

// ---------------- causal flash attention, Q-tile 128, 8 waves ----------------
// No online max (q,k L2-normalized, |score*sc| <= 0.0884 -> exp2 can't
// overflow). Each staged 16KB K/V tile feeds 2x the MFMAs of the Q64 version.
// Ps is WAVE-PRIVATE (each wave writes+reads only its 16-row strip), so the
// P-transpose needs only lgkmcnt(0), not a block barrier: 2 barriers/tile.
#define PLD 68

__global__ __launch_bounds__(512) void flash_attn(
    const u16* __restrict__ QKV, const u16* __restrict__ Vt,
    u16* __restrict__ O) {
  __shared__ u16 Ks[64 * 128];   // slot = row*16 + (g ^ (row&15)), 16B chunks
  __shared__ u16 Vs[128 * 64];   // slot = row*8  + (g ^ (row&7))
  __shared__ u16 Ps[128 * PLD];
  const int tid = threadIdx.x;
  const int lane = tid & 63, wv = tid >> 6;  // wv in [0,8)
  const int cl = lane & 15, qd = lane >> 4;
  const int qbi = blockIdx.x, h = blockIdx.y;
  const int q0 = qbi * 128, kvh = h >> 2;
  const float es = 0.12751629240081506f;  // (1/sqrt(128)) * log2(e)

  // Q fragments straight from global; wave wv owns q-rows q0+wv*16 .. +15
  bf16x8 aQ[4];
  {
    const u16* qrow = QKV + (size_t)(q0 + wv * 16 + cl) * QS + h * HD + qd * 8;
#pragma unroll
    for (int kk = 0; kk < 4; kk++) aQ[kk] = *(const bf16x8*)(qrow + kk * 32);
  }

  f32x4 oacc[8];
  f32x4 zz = {0.f, 0.f, 0.f, 0.f};
#pragma unroll
  for (int n = 0; n < 8; n++) oacc[n] = zz;
  float lsum[4] = {0.f, 0.f, 0.f, 0.f};

  const u16* Kbase = QKV + 4096 + kvh * HD;          // key rows, stride QS
  const u16* Vbase = Vt + (size_t)kvh * HD * S_LEN;  // [d][s], stride S_LEN

  const int row_min = q0 + wv * 16;
  const int ktmax = 2 * qbi + 1;

  for (int kt = 0; kt <= ktmax; kt++) {
    __syncthreads();  // prior iteration's Ks/Vs reads done
    // stage K tile [64 keys][128 d] and V tile [128 d][64 keys]: 1024 16B
    // chunks each, 512 lanes -> 2 rounds
#pragma unroll
    for (int q = 0; q < 2; q++) {
      int c = q * 512 + wv * 64 + lane;
      int kr = c >> 4, kg = (c & 15) ^ (kr & 15);
      async16(Kbase + (size_t)(kt * 64 + kr) * QS + kg * 8,
              Ks + (q * 512 + wv * 64) * 8);
      int vr = c >> 3, vg = (c & 7) ^ (vr & 7);
      async16(Vbase + (size_t)vr * S_LEN + kt * 64 + vg * 8,
              Vs + (q * 512 + wv * 64) * 8);
    }
    __syncthreads();  // vmcnt(0) drain

    if (kt * 64 <= row_min + 15) {  // wave not fully above the diagonal
      // S = Q K^T (this wave: 16 q-rows x 64 keys)
      f32x4 sacc[4];
#pragma unroll
      for (int j = 0; j < 4; j++) sacc[j] = zz;
#pragma unroll
      for (int j = 0; j < 4; j++) {
        int row = j * 16 + cl;
#pragma unroll
        for (int kk = 0; kk < 4; kk++) {
          int ch = (kk * 4 + qd) ^ (row & 15);
          bf16x8 bK = *(const bf16x8*)&Ks[row * 128 + ch * 8];
          sacc[j] = mfma16(aQ[kk], bK, sacc[j]);
        }
      }

      float pm[4][4];
      if (kt * 64 + 63 > row_min) {  // diagonal tile: causal mask
        const int grow = row_min + qd * 4;
#pragma unroll
        for (int j = 0; j < 4; j++) {
          int gcol = kt * 64 + j * 16 + cl;
#pragma unroll
          for (int r = 0; r < 4; r++)
            pm[j][r] = (gcol <= grow + r) ? EXP2(sacc[j][r] * es) : 0.f;
        }
      } else {
#pragma unroll
        for (int j = 0; j < 4; j++)
#pragma unroll
          for (int r = 0; r < 4; r++) pm[j][r] = EXP2(sacc[j][r] * es);
      }
#pragma unroll
      for (int j = 0; j < 4; j++)
#pragma unroll
        for (int r = 0; r < 4; r++) lsum[r] += pm[j][r];

      // P: C-layout -> LDS (A-layout); wave-private strip, no block barrier
#pragma unroll
      for (int j = 0; j < 4; j++)
#pragma unroll
        for (int r = 0; r < 4; r++)
          Ps[(wv * 16 + qd * 4 + r) * PLD + j * 16 + cl] = f2bf(pm[j][r]);
      __asm__ volatile("s_waitcnt lgkmcnt(0)" ::: "memory");

      // O += P V
#pragma unroll
      for (int kk = 0; kk < 2; kk++) {
        bf16x8 aP = *(const bf16x8*)&Ps[(wv * 16 + cl) * PLD + kk * 32 + qd * 8];
#pragma unroll
        for (int n = 0; n < 8; n++) {
          int row = n * 16 + cl;
          int ch = (kk * 4 + qd) ^ (row & 7);
          bf16x8 bV = *(const bf16x8*)&Vs[row * 64 + ch * 8];
          oacc[n] = mfma16(aP, bV, oacc[n]);
        }
      }
    }
  }

  // reduce row sums across the 16-lane column group, write O
#pragma unroll
  for (int r = 0; r < 4; r++) {
#pragma unroll
    for (int off = 8; off >= 1; off >>= 1) lsum[r] += __shfl_xor(lsum[r], off, 64);
  }
#pragma unroll
  for (int r = 0; r < 4; r++) {
    float il = 1.0f / lsum[r];
    int row = row_min + qd * 4 + r;
#pragma unroll
    for (int n = 0; n < 8; n++)
      O[(size_t)row * HID + h * HD + n * 16 + cl] = f2bf(oacc[n][r] * il);
  }
}

// ---------------- launch ----------------
extern "C" void kernel_launch(void* const* d_in, const int* in_sizes, int n_in,
                              void* d_out, int out_size, void* d_ws, size_t ws_size,
                              hipStream_t stream) {
  const float* hs = (const float*)d_in[0];
  const int* pos = (const int*)d_in[1];
  const float* Wq = (const float*)d_in[2];
  const float* Wk = (const float*)d_in[3];
  const float* Wv = (const float*)d_in[4];
  const float* Wo = (const float*)d_in[5];
  const float* qsc = (const float*)d_in[6];
  const float* ksc = (const float*)d_in[7];
  float* out = (float*)d_out;
  char* ws = (char*)d_ws;
  const size_t MB = 1u << 20;

  u16* hs_b  = (u16*)(ws + 0 * MB);   // 16 MB; reused for attention output
  u16* wq_b  = (u16*)(ws + 16 * MB);  // 32 MB  } wq|wk|wv contiguous ->
  u16* wk_b  = (u16*)(ws + 48 * MB);  // 8 MB   }   B[6144][4096]
  u16* wv_b  = (u16*)(ws + 56 * MB);  // 8 MB   }
  u16* qkv_b = (u16*)(ws + 64 * MB);  // 24 MB: [2048][6144] = Q|K|V
  u16* vt_b  = (u16*)(ws + 88 * MB);  // 4 MB: V^T [1024][2048]
  u16* wo_b  = (u16*)(ws + 92 * MB);  // 32 MB
  u16* o_b   = hs_b;                  // hs dead after qkv gemm

  conv_all<<<49152, 256, 0, stream>>>(hs, Wq, Wk, Wv, Wo,
                                      hs_b, wq_b, wk_b, wv_b, wo_b);

  // fused QKV projection: [2048][4096] x [6144][4096]^T -> [2048][6144]
  gemm_bt<<<dim3(QS / 128, S_LEN / 128), 256, 0, stream>>>(
      hs_b, wq_b, qkv_b, nullptr, S_LEN, QS, HID);

  rope_l2norm<<<S_LEN * NH / 4, 256, 0, stream>>>(qkv_b, pos, qsc, NH - 1, 5, QS);
  rope_l2norm<<<S_LEN * NKV / 4, 256, 0, stream>>>(qkv_b + 4096, pos, ksc, NKV - 1, 3, QS);
  transpose_v<<<dim3(S_LEN / 64, (NKV * HD) / 64), 256, 0, stream>>>(qkv_b + 5120, vt_b);

  flash_attn<<<dim3(S_LEN / 128, NH), 512, 0, stream>>>(qkv_b, vt_b, o_b);

  gemm_bt<<<dim3(HID / 128, S_LEN / 128), 256, 0, stream>>>(
      o_b, wo_b, nullptr, out, S_LEN, HID, HID);
}